// Round 7
// baseline (443.064 us; speedup 1.0000x reference)
//
#include <hip/hip_runtime.h>
#include <math.h>

// Problem constants: B=128, L=512, D=300, V=50000, F=1000, FILT=1
#define B_ 128
#define L_ 512
#define D_ 300
#define F_ 1000
#define KPAD 320      // D padded to 10 chunks of 32
#define FPAD 1024     // F padded to 16 tiles of 64
#define NKC 10

// workspace layout (bytes)
#define EHI_OFF 0ull
#define ELO_OFF 41943040ull          // 65536*320*2
#define WHI_OFF 83886080ull
#define WLO_OFF 84541440ull          // +1024*320*2
#define WS_NEED 85196800ull

#define BUFSZ 73728                  // one LDS buffer: A 64K + B 8K

typedef __attribute__((ext_vector_type(8))) short bf16x8;   // 8 bf16 (4 VGPR)
typedef __attribute__((ext_vector_type(4))) float f32x4;

__device__ __forceinline__ void lds16(const void* g, void* l) {
    __builtin_amdgcn_global_load_lds(
        (const __attribute__((address_space(1))) unsigned int*)g,
        (__attribute__((address_space(3))) unsigned int*)l, 16, 0, 0);
}

// ---------------------------------------------------------------- init output
__global__ void init_token_kernel(float* __restrict__ out, const float* __restrict__ fc_b) {
    int i = blockIdx.x * blockDim.x + threadIdx.x;
    if (i < B_ * L_) out[i] = fc_b[1] - fc_b[0];
}

// ------------------------------------------------- E: gather + hi/lo bf16 split
__global__ void convert_E(const int* __restrict__ inp, const float* __restrict__ emb,
                          unsigned int* __restrict__ ehi, unsigned int* __restrict__ elo) {
    unsigned gid = blockIdx.x * 256 + threadIdx.x;
    unsigned row = gid / 160u, pr = gid - row * 160u;
    if (row >= 65536u) return;
    const int tok = inp[row];
    const unsigned d = pr * 2u;
    float x = 0.f, y = 0.f;
    if (d < 300u) {
        float2 v = *(const float2*)(emb + (size_t)tok * D_ + d);
        x = v.x; y = v.y;
    }
    const unsigned bx = __float_as_uint(x), by = __float_as_uint(y);
    const unsigned hx = bx & 0xFFFF0000u, hy = by & 0xFFFF0000u;
    const float lx = x - __uint_as_float(hx);   // exact
    const float ly = y - __uint_as_float(hy);
    ehi[(size_t)row * 160u + pr] = hy | (bx >> 16);
    elo[(size_t)row * 160u + pr] = (__float_as_uint(ly) & 0xFFFF0000u) | (__float_as_uint(lx) >> 16);
}

// ------------------------------------------------- W: hi/lo bf16 split (padded)
__global__ void convert_W(const float* __restrict__ conv_w,
                          unsigned int* __restrict__ whi, unsigned int* __restrict__ wlo) {
    unsigned gid = blockIdx.x * 256 + threadIdx.x;   // 640 blocks: 1024*160
    unsigned f = gid / 160u, pr = gid - f * 160u;
    if (f >= (unsigned)FPAD) return;
    const unsigned d = pr * 2u;
    float x = 0.f, y = 0.f;
    if (f < (unsigned)F_ && d < 300u) {
        float2 v = *(const float2*)(conv_w + (size_t)f * D_ + d);
        x = v.x; y = v.y;
    }
    const unsigned bx = __float_as_uint(x), by = __float_as_uint(y);
    const unsigned hx = bx & 0xFFFF0000u, hy = by & 0xFFFF0000u;
    const float lx = x - __uint_as_float(hx);
    const float ly = y - __uint_as_float(hy);
    whi[(size_t)f * 160u + pr] = hy | (bx >> 16);
    wlo[(size_t)f * 160u + pr] = (__float_as_uint(ly) & 0xFFFF0000u) | (__float_as_uint(lx) >> 16);
}

// ---------------------------------------------------------------- MFMA GEMM
// Block: (b, 64 filters) x all 512 t. 8 waves. 3-pass split-bf16 (hh+hl+lh).
// DOUBLE-BUFFERED 2-phase pipeline: per chunk, vmcnt(0) waits a stage issued a
// full chunk earlier (≈free), then STAGE(c+1)->buf^1 is issued BEFORE the
// ds_read+MFMA of buf c, hiding global_load_lds latency under compute.
// 147456 B LDS -> 1 block/CU (8 waves) by design.
__global__ __launch_bounds__(512, 2)
void gemm_max_scatter(const int* __restrict__ inp,
                      const float* __restrict__ emb,
                      const float* __restrict__ conv_w,
                      const float* __restrict__ conv_b,
                      const float* __restrict__ fc_w,
                      const char* __restrict__ ehi, const char* __restrict__ elo,
                      const char* __restrict__ whi, const char* __restrict__ wlo,
                      float* __restrict__ out) {
    // per buffer: A_hi 0..32K, A_lo 32K..64K, B_hi 64K..68K, B_lo 68K..72K
    __shared__ __align__(16) char smem[2 * BUFSZ];
    const int tid  = threadIdx.x;
    const int lane = tid & 63;
    const int w    = tid >> 6;        // 0..7
    const int a    = lane & 15;       // frag row/col
    const int h    = lane >> 4;       // frag k-slot (8 bf16 each)

    // XCD-chunked swizzle: 16 f-blocks of the same b land on one XCD (L2 reuse).
    const unsigned wg      = blockIdx.x;                 // 0..2047 (2048%8==0: bijective)
    const unsigned logical = (wg & 7u) * 256u + (wg >> 3);
    const int fb    = logical & 15;
    const int b     = logical >> 4;
    const int fBase = fb * 64;

    f32x4 acc[4][4];
#pragma unroll
    for (int mt = 0; mt < 4; ++mt)
#pragma unroll
        for (int nt = 0; nt < 4; ++nt) acc[mt][nt] = (f32x4)(0.f);

    const size_t erow0 = (size_t)b * 512 * KPAD;         // element offset of E slice
    const int    ntB   = w & 3;                          // B subtile this wave stages

#define STAGE(c_, buf_)                                                          \
    {                                                                            \
        const int d0_ = (c_) * 32;                                               \
        _Pragma("unroll")                                                        \
        for (int q = 0; q < 4; ++q) {                                            \
            const int s = w * 4 + q;                                             \
            const size_t src = (erow0 + (size_t)(s * 16 + a) * KPAD + d0_ + h * 8) * 2; \
            lds16(ehi + src, (buf_) + s * 1024);                                 \
            lds16(elo + src, (buf_) + 32768 + s * 1024);                         \
        }                                                                        \
        const size_t srcB = ((size_t)(fBase + ntB * 16 + a) * KPAD + d0_ + h * 8) * 2;  \
        if (w < 4) lds16(whi + srcB, (buf_) + 65536 + ntB * 1024);               \
        else       lds16(wlo + srcB, (buf_) + 69632 + ntB * 1024);               \
    }

    STAGE(0, smem);

    for (int c = 0; c < NKC; ++c) {
        char* cur = smem + (c & 1) * BUFSZ;
        char* nxt = smem + ((c + 1) & 1) * BUFSZ;
        asm volatile("s_waitcnt vmcnt(0)" ::: "memory");  // stage(c) landed
        __syncthreads();                                   // visible to all; prior reads done
        if (c + 1 < NKC) STAGE(c + 1, nxt);                // overlaps reads+MFMA below

        bf16x8 bhi[4], blo[4];
#pragma unroll
        for (int nt = 0; nt < 4; ++nt) {
            bhi[nt] = *(const bf16x8*)(cur + 65536 + nt * 1024 + lane * 16);
            blo[nt] = *(const bf16x8*)(cur + 69632 + nt * 1024 + lane * 16);
        }
#pragma unroll
        for (int mt = 0; mt < 4; ++mt) {
            const int sg = w * 4 + mt;
            const bf16x8 ahi = *(const bf16x8*)(cur + sg * 1024 + lane * 16);
            const bf16x8 alo = *(const bf16x8*)(cur + 32768 + sg * 1024 + lane * 16);
#pragma unroll
            for (int nt = 0; nt < 4; ++nt) {
                acc[mt][nt] = __builtin_amdgcn_mfma_f32_16x16x32_bf16(ahi, bhi[nt], acc[mt][nt], 0, 0, 0);
                acc[mt][nt] = __builtin_amdgcn_mfma_f32_16x16x32_bf16(ahi, blo[nt], acc[mt][nt], 0, 0, 0);
                acc[mt][nt] = __builtin_amdgcn_mfma_f32_16x16x32_bf16(alo, bhi[nt], acc[mt][nt], 0, 0, 0);
            }
        }
    }
    __syncthreads();

    // ---- per-wave top-2 over its 64 t, per filter; tuples to LDS (overlay buf0)
    float4* Tup = (float4*)smem;                          // [8 waves][64 f]
#pragma unroll
    for (int nt = 0; nt < 4; ++nt) {
        float v1 = -INFINITY, v2 = -INFINITY;
        int   i1 = 0, i2 = 0;
#pragma unroll
        for (int mt = 0; mt < 4; ++mt)
#pragma unroll
            for (int r = 0; r < 4; ++r) {                 // ascending t within lane
                const int   t = w * 64 + mt * 16 + h * 4 + r;
                const float v = acc[mt][nt][r];
                if (v > v1)      { v2 = v1; i2 = i1; v1 = v; i1 = t; }
                else if (v > v2) { v2 = v;  i2 = t; }
            }
        // butterfly over the 4 lane-groups sharing f (xor 16, 32)
#pragma unroll
        for (int off = 16; off <= 32; off <<= 1) {
            const float bv1 = __shfl_xor(v1, off);
            const int   bi1 = __shfl_xor(i1, off);
            const float bv2 = __shfl_xor(v2, off);
            const int   bi2 = __shfl_xor(i2, off);
            const bool aTop = (v1 > bv1) || (v1 == bv1 && i1 < bi1);
            float nv1, nv2; int ni1, ni2;
            if (aTop) {
                nv1 = v1; ni1 = i1;
                const bool s = (v2 > bv1) || (v2 == bv1 && i2 < bi1);
                nv2 = s ? v2 : bv1; ni2 = s ? i2 : bi1;
            } else {
                nv1 = bv1; ni1 = bi1;
                const bool s = (bv2 > v1) || (bv2 == v1 && bi2 < i1);
                nv2 = s ? bv2 : v1; ni2 = s ? bi2 : i1;
            }
            v1 = nv1; i1 = ni1; v2 = nv2; i2 = ni2;
        }
        if (lane < 16)
            Tup[w * 64 + nt * 16 + lane] =
                make_float4(v1, __int_as_float(i1), v2, __int_as_float(i2));
    }
    __syncthreads();

    // ---- merge 8 wave-tuples per f; f64 refine only on near-ties; scatter
#pragma unroll 1
    for (int jj = 0; jj < 8; ++jj) {
        const int fr = w * 8 + jj;
        const int gf = fBase + fr;
        if (gf >= F_) continue;                           // wave-uniform
        float v1 = -INFINITY, v2 = -INFINITY;
        int   i1 = 0, i2 = 0;
#pragma unroll 1
        for (int ww = 0; ww < 8; ++ww) {                  // ascending t-ranges
            const float4 tp = Tup[ww * 64 + fr];          // broadcast read
            const float u1 = tp.x, u2 = tp.z;
            const int   j1 = __float_as_int(tp.y), j2 = __float_as_int(tp.w);
            if (u1 > v1) {
                const bool s = (v1 >= u2);                // tie -> earlier index (v-side)
                v2 = s ? v1 : u2; i2 = s ? i1 : j2;
                v1 = u1; i1 = j1;
            } else if (u1 > v2) { v2 = u1; i2 = j1; }
        }
        const float cb = conv_b[gf];
        const float dw = fc_w[F_ + gf] - fc_w[gf];
        double mv = 0.0; int idx = 0;
        if (v1 - v2 > 4e-4f) {                            // gap >> bf16x3 error
            mv = (double)v1 + (double)cb; idx = i1;
        } else {                                          // rare: exact f64 tiebreak
            const float* e1 = emb + (size_t)inp[b * L_ + i1] * D_;
            const float* e2 = emb + (size_t)inp[b * L_ + i2] * D_;
            const float* wf = conv_w + (size_t)gf * D_;
            double p1 = 0.0, p2 = 0.0;
            for (int d = lane; d < D_; d += 64) {
                const double wd = (double)wf[d];
                p1 = fma((double)e1[d], wd, p1);
                p2 = fma((double)e2[d], wd, p2);
            }
            for (int off = 32; off; off >>= 1) {
                p1 += __shfl_down(p1, off);
                p2 += __shfl_down(p2, off);
            }
            const double d1 = p1 + (double)cb, d2 = p2 + (double)cb;  // lane0 valid
            if (d2 > d1) { mv = d2; idx = i2; }
            else         { mv = d1; idx = i1; }
        }
        if (lane == 0 && mv > 0.0)
            atomicAdd(out + b * L_ + idx, (float)(mv * (double)dw));
    }
#undef STAGE
}

// ================= fallback (Round-0 kernel, PASSED) if ws too small =========
#define TFo 32
#define DKo 16
#define NCHo 19
__global__ __launch_bounds__(256, 2)
void conv_max_scatter(const int* __restrict__ inp,
                      const float* __restrict__ emb,
                      const float* __restrict__ conv_w,
                      const float* __restrict__ conv_b,
                      const float* __restrict__ fc_w,
                      float* __restrict__ out) {
    __shared__ float E_s[DKo][L_];
    __shared__ float W_s[DKo][TFo + 1];
    __shared__ int   inp_s[L_];
    const int tid = threadIdx.x, b = blockIdx.y, fBase = blockIdx.x * TFo;
    const int lane = tid & 63, wave = tid >> 6, f0 = wave * 8;
    inp_s[tid] = inp[b * L_ + tid];
    inp_s[tid + 256] = inp[b * L_ + tid + 256];
    __syncthreads();
    float acc[8][8];
#pragma unroll
    for (int k = 0; k < 8; ++k)
#pragma unroll
        for (int j = 0; j < 8; ++j) acc[k][j] = 0.f;
    for (int c = 0; c < NCHo; ++c) {
        const int d0 = c * DKo;
#pragma unroll
        for (int e = 0; e < 2; ++e) {
            const int t = tid * 2 + e;
            const float* rowp = emb + (size_t)inp_s[t] * D_ + d0;
#pragma unroll
            for (int s = 0; s < 4; ++s) {
                float4 v;
                if (d0 + s * 4 < D_) v = *(const float4*)(rowp + s * 4);
                else                 v = make_float4(0.f, 0.f, 0.f, 0.f);
                E_s[s * 4 + 0][t] = v.x; E_s[s * 4 + 1][t] = v.y;
                E_s[s * 4 + 2][t] = v.z; E_s[s * 4 + 3][t] = v.w;
            }
        }
#pragma unroll
        for (int e = 0; e < 2; ++e) {
            const int d = tid & 15, f = (tid >> 4) + e * 16, gf = fBase + f;
            float v = 0.f;
            if (gf < F_ && d0 + d < D_) v = conv_w[(size_t)gf * D_ + d0 + d];
            W_s[d][f] = v;
        }
        __syncthreads();
#pragma unroll
        for (int d = 0; d < DKo; ++d) {
            float wv[8], ev[8];
#pragma unroll
            for (int j = 0; j < 8; ++j) wv[j] = W_s[d][f0 + j];
#pragma unroll
            for (int k = 0; k < 8; ++k) ev[k] = E_s[d][lane + 64 * k];
#pragma unroll
            for (int k = 0; k < 8; ++k)
#pragma unroll
                for (int j = 0; j < 8; ++j) acc[k][j] = fmaf(ev[k], wv[j], acc[k][j]);
        }
        __syncthreads();
    }
    float v1a[8], v2a[8]; int i1a[8], i2a[8];
#pragma unroll
    for (int j = 0; j < 8; ++j) {
        float v1 = -INFINITY, v2 = -INFINITY; int i1 = 0, i2 = 0;
#pragma unroll
        for (int k = 0; k < 8; ++k) {
            const int t = lane + 64 * k; const float v = acc[k][j];
            if (v > v1) { v2 = v1; i2 = i1; v1 = v; i1 = t; }
            else if (v > v2) { v2 = v; i2 = t; }
        }
        for (int off = 1; off < 64; off <<= 1) {
            const float bv1 = __shfl_xor(v1, off); const int bi1 = __shfl_xor(i1, off);
            const float bv2 = __shfl_xor(v2, off); const int bi2 = __shfl_xor(i2, off);
            const bool aTop = (v1 > bv1) || (v1 == bv1 && i1 < bi1);
            float nv1, nv2; int ni1, ni2;
            if (aTop) {
                nv1 = v1; ni1 = i1;
                const bool s = (v2 > bv1) || (v2 == bv1 && i2 < bi1);
                nv2 = s ? v2 : bv1; ni2 = s ? i2 : bi1;
            } else {
                nv1 = bv1; ni1 = bi1;
                const bool s = (bv2 > v1) || (bv2 == v1 && bi2 < i1);
                nv2 = s ? bv2 : v1; ni2 = s ? bi2 : i1;
            }
            v1 = nv1; i1 = ni1; v2 = nv2; i2 = ni2;
        }
        v1a[j] = v1; i1a[j] = i1; v2a[j] = v2; i2a[j] = i2;
    }
#pragma unroll 1
    for (int j = 0; j < 8; ++j) {
        const int gf = fBase + f0 + j;
        if (gf >= F_) continue;
        const int i1 = i1a[j], i2 = i2a[j];
        const float* e1 = emb + (size_t)inp_s[i1] * D_;
        const float* e2 = emb + (size_t)inp_s[i2] * D_;
        const float* wf = conv_w + (size_t)gf * D_;
        double p1 = 0.0, p2 = 0.0;
        for (int d = lane; d < D_; d += 64) {
            const double wd = (double)wf[d];
            p1 = fma((double)e1[d], wd, p1);
            p2 = fma((double)e2[d], wd, p2);
        }
        for (int off = 32; off; off >>= 1) { p1 += __shfl_down(p1, off); p2 += __shfl_down(p2, off); }
        if (lane == 0) {
            const double cb = (double)conv_b[gf];
            const double d1 = p1 + cb, d2 = p2 + cb;
            int idx; double mv;
            if (d2 > d1) { idx = i2; mv = d2; } else { idx = i1; mv = d1; }
            if (mv > 0.0)
                atomicAdd(&out[b * L_ + idx], (float)(mv * (double)(fc_w[F_ + gf] - fc_w[gf])));
        }
    }
}

// ============================================================================
extern "C" void kernel_launch(void* const* d_in, const int* in_sizes, int n_in,
                              void* d_out, int out_size, void* d_ws, size_t ws_size,
                              hipStream_t stream) {
    const int*   inp    = (const int*)d_in[0];
    const float* emb    = (const float*)d_in[1];
    const float* conv_w = (const float*)d_in[2];
    const float* conv_b = (const float*)d_in[3];
    const float* fc_w   = (const float*)d_in[4];
    const float* fc_b   = (const float*)d_in[5];
    float* out = (float*)d_out;

    init_token_kernel<<<dim3((B_ * L_ + 255) / 256), dim3(256), 0, stream>>>(out, fc_b);

    if (ws_size >= WS_NEED) {
        char* ws = (char*)d_ws;
        unsigned int* ehi = (unsigned int*)(ws + EHI_OFF);
        unsigned int* elo = (unsigned int*)(ws + ELO_OFF);
        unsigned int* whi = (unsigned int*)(ws + WHI_OFF);
        unsigned int* wlo = (unsigned int*)(ws + WLO_OFF);
        convert_E<<<dim3(40960), dim3(256), 0, stream>>>(inp, emb, ehi, elo);
        convert_W<<<dim3(640),   dim3(256), 0, stream>>>(conv_w, whi, wlo);
        gemm_max_scatter<<<dim3(2048), dim3(512), 0, stream>>>(
            inp, emb, conv_w, conv_b, fc_w,
            (const char*)ehi, (const char*)elo, (const char*)whi, (const char*)wlo, out);
    } else {
        conv_max_scatter<<<dim3(32, 128), dim3(256), 0, stream>>>(
            inp, emb, conv_w, conv_b, fc_w, out);
    }
}

// Round 8
// 442.934 us; speedup vs baseline: 1.0003x; 1.0003x over previous
//
#include <hip/hip_runtime.h>
#include <math.h>

// Problem constants: B=128, L=512, D=300, V=50000, F=1000, FILT=1
#define B_ 128
#define L_ 512
#define D_ 300
#define F_ 1000
#define KPAD 320      // D padded to 10 chunks of 32
#define FPAD 1024     // F padded to 16 tiles of 64
#define NKC 10

// workspace layout (bytes)
#define EHI_OFF 0ull
#define ELO_OFF 41943040ull          // 65536*320*2
#define WHI_OFF 83886080ull
#define WLO_OFF 84541440ull          // +1024*320*2
#define WS_NEED 85196800ull

#define BUFSZ 73728                  // one LDS buffer: A 64K + B 8K

typedef __attribute__((ext_vector_type(8))) short bf16x8;   // 8 bf16 (4 VGPR)
typedef __attribute__((ext_vector_type(4))) float f32x4;

__device__ __forceinline__ void lds16(const void* g, void* l) {
    __builtin_amdgcn_global_load_lds(
        (const __attribute__((address_space(1))) unsigned int*)g,
        (__attribute__((address_space(3))) unsigned int*)l, 16, 0, 0);
}

// ---------------------------------------------------------------- init output
__global__ void init_token_kernel(float* __restrict__ out, const float* __restrict__ fc_b) {
    int i = blockIdx.x * blockDim.x + threadIdx.x;
    if (i < B_ * L_) out[i] = fc_b[1] - fc_b[0];
}

// ------------------------------------------------- E: gather + hi/lo bf16 split
__global__ void convert_E(const int* __restrict__ inp, const float* __restrict__ emb,
                          unsigned int* __restrict__ ehi, unsigned int* __restrict__ elo) {
    unsigned gid = blockIdx.x * 256 + threadIdx.x;
    unsigned row = gid / 160u, pr = gid - row * 160u;
    if (row >= 65536u) return;
    const int tok = inp[row];
    const unsigned d = pr * 2u;
    float x = 0.f, y = 0.f;
    if (d < 300u) {
        float2 v = *(const float2*)(emb + (size_t)tok * D_ + d);
        x = v.x; y = v.y;
    }
    const unsigned bx = __float_as_uint(x), by = __float_as_uint(y);
    const unsigned hx = bx & 0xFFFF0000u, hy = by & 0xFFFF0000u;
    const float lx = x - __uint_as_float(hx);   // exact
    const float ly = y - __uint_as_float(hy);
    ehi[(size_t)row * 160u + pr] = hy | (bx >> 16);
    elo[(size_t)row * 160u + pr] = (__float_as_uint(ly) & 0xFFFF0000u) | (__float_as_uint(lx) >> 16);
}

// ------------------------------------------------- W: hi/lo bf16 split (padded)
__global__ void convert_W(const float* __restrict__ conv_w,
                          unsigned int* __restrict__ whi, unsigned int* __restrict__ wlo) {
    unsigned gid = blockIdx.x * 256 + threadIdx.x;   // 640 blocks: 1024*160
    unsigned f = gid / 160u, pr = gid - f * 160u;
    if (f >= (unsigned)FPAD) return;
    const unsigned d = pr * 2u;
    float x = 0.f, y = 0.f;
    if (f < (unsigned)F_ && d < 300u) {
        float2 v = *(const float2*)(conv_w + (size_t)f * D_ + d);
        x = v.x; y = v.y;
    }
    const unsigned bx = __float_as_uint(x), by = __float_as_uint(y);
    const unsigned hx = bx & 0xFFFF0000u, hy = by & 0xFFFF0000u;
    const float lx = x - __uint_as_float(hx);
    const float ly = y - __uint_as_float(hy);
    whi[(size_t)f * 160u + pr] = hy | (bx >> 16);
    wlo[(size_t)f * 160u + pr] = (__float_as_uint(ly) & 0xFFFF0000u) | (__float_as_uint(lx) >> 16);
}

// ---------------------------------------------------------------- MFMA GEMM
// Block: (b, 64 filters) x all 512 t. 8 waves. 3-pass split-bf16 (hh+hl+lh).
// Double-buffered with COUNTED vmcnt (T4): STAGE issues 9 global_load_lds per
// wave; vmcnt(9) waits only for the PREVIOUS chunk's loads (issued one full
// iteration earlier => ~free). Raw s_barrier avoids __syncthreads' forced
// vmcnt(0) drain; sched_barrier(0) fences stop hipcc hoisting across waits
// (rule #18). 147456 B LDS -> 1 block/CU (8 waves).
__global__ __launch_bounds__(512, 2)
void gemm_max_scatter(const int* __restrict__ inp,
                      const float* __restrict__ emb,
                      const float* __restrict__ conv_w,
                      const float* __restrict__ conv_b,
                      const float* __restrict__ fc_w,
                      const char* __restrict__ ehi, const char* __restrict__ elo,
                      const char* __restrict__ whi, const char* __restrict__ wlo,
                      float* __restrict__ out) {
    // per buffer: A_hi 0..32K, A_lo 32K..64K, B_hi 64K..68K, B_lo 68K..72K
    __shared__ __align__(16) char smem[2 * BUFSZ];
    const int tid  = threadIdx.x;
    const int lane = tid & 63;
    const int w    = tid >> 6;        // 0..7
    const int a    = lane & 15;       // frag row/col
    const int h    = lane >> 4;       // frag k-slot (8 bf16 each)

    // XCD-chunked swizzle: 16 f-blocks of the same b land on one XCD (L2 reuse).
    const unsigned wg      = blockIdx.x;                 // 0..2047 (2048%8==0: bijective)
    const unsigned logical = (wg & 7u) * 256u + (wg >> 3);
    const int fb    = logical & 15;
    const int b     = logical >> 4;
    const int fBase = fb * 64;

    f32x4 acc[4][4];
#pragma unroll
    for (int mt = 0; mt < 4; ++mt)
#pragma unroll
        for (int nt = 0; nt < 4; ++nt) acc[mt][nt] = (f32x4)(0.f);

    const size_t erow0 = (size_t)b * 512 * KPAD;         // element offset of E slice
    const int    ntB   = w & 3;                          // B subtile this wave stages

    // 9 global_load_lds per wave per STAGE (8 A + 1 B) — vmcnt counts these.
#define STAGE(c_, buf_)                                                          \
    {                                                                            \
        const int d0_ = (c_) * 32;                                               \
        _Pragma("unroll")                                                        \
        for (int q = 0; q < 4; ++q) {                                            \
            const int s = w * 4 + q;                                             \
            const size_t src = (erow0 + (size_t)(s * 16 + a) * KPAD + d0_ + h * 8) * 2; \
            lds16(ehi + src, (buf_) + s * 1024);                                 \
            lds16(elo + src, (buf_) + 32768 + s * 1024);                         \
        }                                                                        \
        const size_t srcB = ((size_t)(fBase + ntB * 16 + a) * KPAD + d0_ + h * 8) * 2;  \
        if (w < 4) lds16(whi + srcB, (buf_) + 65536 + ntB * 1024);               \
        else       lds16(wlo + srcB, (buf_) + 69632 + ntB * 1024);               \
    }

    STAGE(0, smem);

    for (int c = 0; c < NKC; ++c) {
        char* cur = smem + (c & 1) * BUFSZ;
        char* nxt = smem + ((c + 1) & 1) * BUFSZ;
        if (c + 1 < NKC) {
            STAGE(c + 1, nxt);                              // prefetch (9 more in flight)
            asm volatile("s_waitcnt vmcnt(9)" ::: "memory"); // chunk-c's 9 retired (in-order)
        } else {
            asm volatile("s_waitcnt vmcnt(0)" ::: "memory"); // last chunk: full drain
        }
        __builtin_amdgcn_sched_barrier(0);
        __builtin_amdgcn_s_barrier();                        // raw: no compiler vmcnt(0) drain
        __builtin_amdgcn_sched_barrier(0);

        bf16x8 bhi[4], blo[4];
#pragma unroll
        for (int nt = 0; nt < 4; ++nt) {
            bhi[nt] = *(const bf16x8*)(cur + 65536 + nt * 1024 + lane * 16);
            blo[nt] = *(const bf16x8*)(cur + 69632 + nt * 1024 + lane * 16);
        }
#pragma unroll
        for (int mt = 0; mt < 4; ++mt) {
            const int sg = w * 4 + mt;                       // same subtiles this wave staged
            const bf16x8 ahi = *(const bf16x8*)(cur + sg * 1024 + lane * 16);
            const bf16x8 alo = *(const bf16x8*)(cur + 32768 + sg * 1024 + lane * 16);
#pragma unroll
            for (int nt = 0; nt < 4; ++nt) {
                acc[mt][nt] = __builtin_amdgcn_mfma_f32_16x16x32_bf16(ahi, bhi[nt], acc[mt][nt], 0, 0, 0);
                acc[mt][nt] = __builtin_amdgcn_mfma_f32_16x16x32_bf16(ahi, blo[nt], acc[mt][nt], 0, 0, 0);
                acc[mt][nt] = __builtin_amdgcn_mfma_f32_16x16x32_bf16(alo, bhi[nt], acc[mt][nt], 0, 0, 0);
            }
        }
        __builtin_amdgcn_sched_barrier(0);
        __builtin_amdgcn_s_barrier();                        // all reads of cur done
        __builtin_amdgcn_sched_barrier(0);                   // next STAGE must not hoist above
    }
    __syncthreads();

    // ---- per-wave top-2 over its 64 t, per filter; tuples to LDS (overlay buf0)
    float4* Tup = (float4*)smem;                          // [8 waves][64 f]
#pragma unroll
    for (int nt = 0; nt < 4; ++nt) {
        float v1 = -INFINITY, v2 = -INFINITY;
        int   i1 = 0, i2 = 0;
#pragma unroll
        for (int mt = 0; mt < 4; ++mt)
#pragma unroll
            for (int r = 0; r < 4; ++r) {                 // ascending t within lane
                const int   t = w * 64 + mt * 16 + h * 4 + r;
                const float v = acc[mt][nt][r];
                if (v > v1)      { v2 = v1; i2 = i1; v1 = v; i1 = t; }
                else if (v > v2) { v2 = v;  i2 = t; }
            }
        // butterfly over the 4 lane-groups sharing f (xor 16, 32)
#pragma unroll
        for (int off = 16; off <= 32; off <<= 1) {
            const float bv1 = __shfl_xor(v1, off);
            const int   bi1 = __shfl_xor(i1, off);
            const float bv2 = __shfl_xor(v2, off);
            const int   bi2 = __shfl_xor(i2, off);
            const bool aTop = (v1 > bv1) || (v1 == bv1 && i1 < bi1);
            float nv1, nv2; int ni1, ni2;
            if (aTop) {
                nv1 = v1; ni1 = i1;
                const bool s = (v2 > bv1) || (v2 == bv1 && i2 < bi1);
                nv2 = s ? v2 : bv1; ni2 = s ? i2 : bi1;
            } else {
                nv1 = bv1; ni1 = bi1;
                const bool s = (bv2 > v1) || (bv2 == v1 && bi2 < i1);
                nv2 = s ? bv2 : v1; ni2 = s ? bi2 : i1;
            }
            v1 = nv1; i1 = ni1; v2 = nv2; i2 = ni2;
        }
        if (lane < 16)
            Tup[w * 64 + nt * 16 + lane] =
                make_float4(v1, __int_as_float(i1), v2, __int_as_float(i2));
    }
    __syncthreads();

    // ---- merge 8 wave-tuples per f; f64 refine only on near-ties; scatter
#pragma unroll 1
    for (int jj = 0; jj < 8; ++jj) {
        const int fr = w * 8 + jj;
        const int gf = fBase + fr;
        if (gf >= F_) continue;                           // wave-uniform
        float v1 = -INFINITY, v2 = -INFINITY;
        int   i1 = 0, i2 = 0;
#pragma unroll 1
        for (int ww = 0; ww < 8; ++ww) {                  // ascending t-ranges
            const float4 tp = Tup[ww * 64 + fr];          // broadcast read
            const float u1 = tp.x, u2 = tp.z;
            const int   j1 = __float_as_int(tp.y), j2 = __float_as_int(tp.w);
            if (u1 > v1) {
                const bool s = (v1 >= u2);                // tie -> earlier index (v-side)
                v2 = s ? v1 : u2; i2 = s ? i1 : j2;
                v1 = u1; i1 = j1;
            } else if (u1 > v2) { v2 = u1; i2 = j1; }
        }
        const float cb = conv_b[gf];
        const float dw = fc_w[F_ + gf] - fc_w[gf];
        double mv = 0.0; int idx = 0;
        if (v1 - v2 > 4e-4f) {                            // gap >> bf16x3 error
            mv = (double)v1 + (double)cb; idx = i1;
        } else {                                          // rare: exact f64 tiebreak
            const float* e1 = emb + (size_t)inp[b * L_ + i1] * D_;
            const float* e2 = emb + (size_t)inp[b * L_ + i2] * D_;
            const float* wf = conv_w + (size_t)gf * D_;
            double p1 = 0.0, p2 = 0.0;
            for (int d = lane; d < D_; d += 64) {
                const double wd = (double)wf[d];
                p1 = fma((double)e1[d], wd, p1);
                p2 = fma((double)e2[d], wd, p2);
            }
            for (int off = 32; off; off >>= 1) {
                p1 += __shfl_down(p1, off);
                p2 += __shfl_down(p2, off);
            }
            const double d1 = p1 + (double)cb, d2 = p2 + (double)cb;  // lane0 valid
            if (d2 > d1) { mv = d2; idx = i2; }
            else         { mv = d1; idx = i1; }
        }
        if (lane == 0 && mv > 0.0)
            atomicAdd(out + b * L_ + idx, (float)(mv * (double)dw));
    }
#undef STAGE
}

// ================= fallback (Round-0 kernel, PASSED) if ws too small =========
#define TFo 32
#define DKo 16
#define NCHo 19
__global__ __launch_bounds__(256, 2)
void conv_max_scatter(const int* __restrict__ inp,
                      const float* __restrict__ emb,
                      const float* __restrict__ conv_w,
                      const float* __restrict__ conv_b,
                      const float* __restrict__ fc_w,
                      float* __restrict__ out) {
    __shared__ float E_s[DKo][L_];
    __shared__ float W_s[DKo][TFo + 1];
    __shared__ int   inp_s[L_];
    const int tid = threadIdx.x, b = blockIdx.y, fBase = blockIdx.x * TFo;
    const int lane = tid & 63, wave = tid >> 6, f0 = wave * 8;
    inp_s[tid] = inp[b * L_ + tid];
    inp_s[tid + 256] = inp[b * L_ + tid + 256];
    __syncthreads();
    float acc[8][8];
#pragma unroll
    for (int k = 0; k < 8; ++k)
#pragma unroll
        for (int j = 0; j < 8; ++j) acc[k][j] = 0.f;
    for (int c = 0; c < NCHo; ++c) {
        const int d0 = c * DKo;
#pragma unroll
        for (int e = 0; e < 2; ++e) {
            const int t = tid * 2 + e;
            const float* rowp = emb + (size_t)inp_s[t] * D_ + d0;
#pragma unroll
            for (int s = 0; s < 4; ++s) {
                float4 v;
                if (d0 + s * 4 < D_) v = *(const float4*)(rowp + s * 4);
                else                 v = make_float4(0.f, 0.f, 0.f, 0.f);
                E_s[s * 4 + 0][t] = v.x; E_s[s * 4 + 1][t] = v.y;
                E_s[s * 4 + 2][t] = v.z; E_s[s * 4 + 3][t] = v.w;
            }
        }
#pragma unroll
        for (int e = 0; e < 2; ++e) {
            const int d = tid & 15, f = (tid >> 4) + e * 16, gf = fBase + f;
            float v = 0.f;
            if (gf < F_ && d0 + d < D_) v = conv_w[(size_t)gf * D_ + d0 + d];
            W_s[d][f] = v;
        }
        __syncthreads();
#pragma unroll
        for (int d = 0; d < DKo; ++d) {
            float wv[8], ev[8];
#pragma unroll
            for (int j = 0; j < 8; ++j) wv[j] = W_s[d][f0 + j];
#pragma unroll
            for (int k = 0; k < 8; ++k) ev[k] = E_s[d][lane + 64 * k];
#pragma unroll
            for (int k = 0; k < 8; ++k)
#pragma unroll
                for (int j = 0; j < 8; ++j) acc[k][j] = fmaf(ev[k], wv[j], acc[k][j]);
        }
        __syncthreads();
    }
    float v1a[8], v2a[8]; int i1a[8], i2a[8];
#pragma unroll
    for (int j = 0; j < 8; ++j) {
        float v1 = -INFINITY, v2 = -INFINITY; int i1 = 0, i2 = 0;
#pragma unroll
        for (int k = 0; k < 8; ++k) {
            const int t = lane + 64 * k; const float v = acc[k][j];
            if (v > v1) { v2 = v1; i2 = i1; v1 = v; i1 = t; }
            else if (v > v2) { v2 = v; i2 = t; }
        }
        for (int off = 1; off < 64; off <<= 1) {
            const float bv1 = __shfl_xor(v1, off); const int bi1 = __shfl_xor(i1, off);
            const float bv2 = __shfl_xor(v2, off); const int bi2 = __shfl_xor(i2, off);
            const bool aTop = (v1 > bv1) || (v1 == bv1 && i1 < bi1);
            float nv1, nv2; int ni1, ni2;
            if (aTop) {
                nv1 = v1; ni1 = i1;
                const bool s = (v2 > bv1) || (v2 == bv1 && i2 < bi1);
                nv2 = s ? v2 : bv1; ni2 = s ? i2 : bi1;
            } else {
                nv1 = bv1; ni1 = bi1;
                const bool s = (bv2 > v1) || (bv2 == v1 && bi2 < i1);
                nv2 = s ? bv2 : v1; ni2 = s ? bi2 : i1;
            }
            v1 = nv1; i1 = ni1; v2 = nv2; i2 = ni2;
        }
        v1a[j] = v1; i1a[j] = i1; v2a[j] = v2; i2a[j] = i2;
    }
#pragma unroll 1
    for (int j = 0; j < 8; ++j) {
        const int gf = fBase + f0 + j;
        if (gf >= F_) continue;
        const int i1 = i1a[j], i2 = i2a[j];
        const float* e1 = emb + (size_t)inp_s[i1] * D_;
        const float* e2 = emb + (size_t)inp_s[i2] * D_;
        const float* wf = conv_w + (size_t)gf * D_;
        double p1 = 0.0, p2 = 0.0;
        for (int d = lane; d < D_; d += 64) {
            const double wd = (double)wf[d];
            p1 = fma((double)e1[d], wd, p1);
            p2 = fma((double)e2[d], wd, p2);
        }
        for (int off = 32; off; off >>= 1) { p1 += __shfl_down(p1, off); p2 += __shfl_down(p2, off); }
        if (lane == 0) {
            const double cb = (double)conv_b[gf];
            const double d1 = p1 + cb, d2 = p2 + cb;
            int idx; double mv;
            if (d2 > d1) { idx = i2; mv = d2; } else { idx = i1; mv = d1; }
            if (mv > 0.0)
                atomicAdd(&out[b * L_ + idx], (float)(mv * (double)(fc_w[F_ + gf] - fc_w[gf])));
        }
    }
}

// ============================================================================
extern "C" void kernel_launch(void* const* d_in, const int* in_sizes, int n_in,
                              void* d_out, int out_size, void* d_ws, size_t ws_size,
                              hipStream_t stream) {
    const int*   inp    = (const int*)d_in[0];
    const float* emb    = (const float*)d_in[1];
    const float* conv_w = (const float*)d_in[2];
    const float* conv_b = (const float*)d_in[3];
    const float* fc_w   = (const float*)d_in[4];
    const float* fc_b   = (const float*)d_in[5];
    float* out = (float*)d_out;

    init_token_kernel<<<dim3((B_ * L_ + 255) / 256), dim3(256), 0, stream>>>(out, fc_b);

    if (ws_size >= WS_NEED) {
        char* ws = (char*)d_ws;
        unsigned int* ehi = (unsigned int*)(ws + EHI_OFF);
        unsigned int* elo = (unsigned int*)(ws + ELO_OFF);
        unsigned int* whi = (unsigned int*)(ws + WHI_OFF);
        unsigned int* wlo = (unsigned int*)(ws + WLO_OFF);
        convert_E<<<dim3(40960), dim3(256), 0, stream>>>(inp, emb, ehi, elo);
        convert_W<<<dim3(640),   dim3(256), 0, stream>>>(conv_w, whi, wlo);
        gemm_max_scatter<<<dim3(2048), dim3(512), 0, stream>>>(
            inp, emb, conv_w, conv_b, fc_w,
            (const char*)ehi, (const char*)elo, (const char*)whi, (const char*)wlo, out);
    } else {
        conv_max_scatter<<<dim3(32, 128), dim3(256), 0, stream>>>(
            inp, emb, conv_w, conv_b, fc_w, out);
    }
}

// Round 11
// 386.476 us; speedup vs baseline: 1.1464x; 1.1461x over previous
//
#include <hip/hip_runtime.h>
#include <math.h>

// Problem constants: B=128, L=512, D=300, V=50000, F=1000, FILT=1
#define B_ 128
#define L_ 512
#define D_ 300
#define F_ 1000
#define KPAD 320      // D padded to 10 chunks of 32
#define FPAD 1024     // F padded to 16 tiles of 64
#define NKC 10

// workspace layout (bytes)
#define EHI_OFF 0ull
#define ELO_OFF 41943040ull          // 65536*320*2
#define WHI_OFF 83886080ull
#define WLO_OFF 84541440ull          // +1024*320*2
#define WS_NEED 85196800ull

typedef __attribute__((ext_vector_type(8))) short bf16x8;   // 8 bf16 (4 VGPR)
typedef __attribute__((ext_vector_type(4))) float f32x4;

__device__ __forceinline__ void lds16(const void* g, void* l) {
    __builtin_amdgcn_global_load_lds(
        (const __attribute__((address_space(1))) unsigned int*)g,
        (__attribute__((address_space(3))) unsigned int*)l, 16, 0, 0);
}

// ---------------------------------------------------------------- init output
__global__ void init_token_kernel(float* __restrict__ out, const float* __restrict__ fc_b) {
    int i = blockIdx.x * blockDim.x + threadIdx.x;
    if (i < B_ * L_) out[i] = fc_b[1] - fc_b[0];
}

// ------------------------------------------------- E: gather + hi/lo bf16 split
__global__ void convert_E(const int* __restrict__ inp, const float* __restrict__ emb,
                          unsigned int* __restrict__ ehi, unsigned int* __restrict__ elo) {
    unsigned gid = blockIdx.x * 256 + threadIdx.x;
    unsigned row = gid / 160u, pr = gid - row * 160u;
    if (row >= 65536u) return;
    const int tok = inp[row];
    const unsigned d = pr * 2u;
    float x = 0.f, y = 0.f;
    if (d < 300u) {
        float2 v = *(const float2*)(emb + (size_t)tok * D_ + d);
        x = v.x; y = v.y;
    }
    const unsigned bx = __float_as_uint(x), by = __float_as_uint(y);
    const unsigned hx = bx & 0xFFFF0000u, hy = by & 0xFFFF0000u;
    const float lx = x - __uint_as_float(hx);   // exact
    const float ly = y - __uint_as_float(hy);
    ehi[(size_t)row * 160u + pr] = hy | (bx >> 16);
    elo[(size_t)row * 160u + pr] = (__float_as_uint(ly) & 0xFFFF0000u) | (__float_as_uint(lx) >> 16);
}

// ------------------------------------------------- W: hi/lo bf16 split (padded)
__global__ void convert_W(const float* __restrict__ conv_w,
                          unsigned int* __restrict__ whi, unsigned int* __restrict__ wlo) {
    unsigned gid = blockIdx.x * 256 + threadIdx.x;   // 640 blocks: 1024*160
    unsigned f = gid / 160u, pr = gid - f * 160u;
    if (f >= (unsigned)FPAD) return;
    const unsigned d = pr * 2u;
    float x = 0.f, y = 0.f;
    if (f < (unsigned)F_ && d < 300u) {
        float2 v = *(const float2*)(conv_w + (size_t)f * D_ + d);
        x = v.x; y = v.y;
    }
    const unsigned bx = __float_as_uint(x), by = __float_as_uint(y);
    const unsigned hx = bx & 0xFFFF0000u, hy = by & 0xFFFF0000u;
    const float lx = x - __uint_as_float(hx);
    const float ly = y - __uint_as_float(hy);
    whi[(size_t)f * 160u + pr] = hy | (bx >> 16);
    wlo[(size_t)f * 160u + pr] = (__float_as_uint(ly) & 0xFFFF0000u) | (__float_as_uint(lx) >> 16);
}

// ---------------------------------------------------------------- MFMA GEMM v3
// Key change vs R3-R7: A (E) has ZERO cross-wave sharing -> load it straight
// global->VGPR as MFMA fragments (per-lane dwordx4 at the frag address).
// Only B (W, 8KB/chunk) goes through LDS: 4-slot ring, staged 1 chunk ahead,
// ONE raw s_barrier per chunk + counted vmcnt(9) (retires only B(c); the A(c)
// reg-load waits are compiler-tracked). Ring distance: writer (c+1)&3 vs live
// readers (c-1)&3 / c&3 -> race-free. 32KB LDS, ~120 VGPR -> 2 blocks/CU.
__global__ __launch_bounds__(512, 4)
void gemm_max_scatter(const int* __restrict__ inp,
                      const float* __restrict__ emb,
                      const float* __restrict__ conv_w,
                      const float* __restrict__ conv_b,
                      const float* __restrict__ fc_w,
                      const char* __restrict__ ehi, const char* __restrict__ elo,
                      const char* __restrict__ whi, const char* __restrict__ wlo,
                      float* __restrict__ out) {
    // B ring: slot s at s*8192; hi = nt*1024, lo = 4096 + nt*1024
    __shared__ __align__(16) char smem[4 * 8192];
    const int tid  = threadIdx.x;
    const int lane = tid & 63;
    const int w    = tid >> 6;        // 0..7
    const int a    = lane & 15;       // frag row/col
    const int h    = lane >> 4;       // frag k-slot (8 bf16 each)

    // XCD-chunked swizzle: 16 f-blocks of the same b land on one XCD (L2 reuse).
    const unsigned wg      = blockIdx.x;                 // 0..2047 (2048%8==0: bijective)
    const unsigned logical = (wg & 7u) * 256u + (wg >> 3);
    const int fb    = logical & 15;
    const int b     = logical >> 4;
    const int fBase = fb * 64;

    f32x4 acc[4][4];
#pragma unroll
    for (int mt = 0; mt < 4; ++mt)
#pragma unroll
        for (int nt = 0; nt < 4; ++nt) acc[mt][nt] = (f32x4)(0.f);

    const size_t erow0 = (size_t)b * 512 * KPAD;         // element offset of E slice
    const int    ntB   = w & 3;                          // B subtile this wave stages

    // per-lane A fragment base (bytes); advance +64 per chunk, +10240 per mt
    const size_t aoff = (erow0 + (size_t)(w * 64 + a) * KPAD + h * 8) * 2;
    const char* pAhi = ehi + aoff;
    const char* pAlo = elo + aoff;
    // B staging source (per wave) and LDS dest offset
    const char* pBsrc = (w < 4 ? whi : wlo) +
                        ((size_t)(fBase + ntB * 16 + a) * KPAD + h * 8) * 2;
    const int   bdst  = (w < 4 ? 0 : 4096) + ntB * 1024;

    lds16(pBsrc, smem + bdst);                            // stage B(0) -> slot 0

    for (int c = 0; c < NKC; ++c) {
        const int coff = c * 64;
        // A(c): 8 per-lane reg loads (compiler-tracked vmcnt deps)
        bf16x8 ahi[4], alo[4];
#pragma unroll
        for (int mt = 0; mt < 4; ++mt)
            ahi[mt] = *(const bf16x8*)(pAhi + mt * 10240 + coff);
#pragma unroll
        for (int mt = 0; mt < 4; ++mt)
            alo[mt] = *(const bf16x8*)(pAlo + mt * 10240 + coff);
        // stage B(c+1) one ahead, then retire exactly B(c) (counted vmcnt)
        if (c + 1 < NKC) {
            lds16(pBsrc + coff + 64, smem + (((c + 1) & 3) * 8192) + bdst);
            asm volatile("s_waitcnt vmcnt(9)" ::: "memory"); // 9 newer: A(c)x8+B(c+1)
        } else {
            asm volatile("s_waitcnt vmcnt(8)" ::: "memory"); // 8 newer: A(c)x8
        }
        asm volatile("s_barrier" ::: "memory");              // B(c) visible to all
        const char* bs = smem + (c & 3) * 8192;
#pragma unroll
        for (int nt = 0; nt < 4; ++nt) {
            const bf16x8 bh = *(const bf16x8*)(bs + nt * 1024 + lane * 16);
            const bf16x8 bl = *(const bf16x8*)(bs + 4096 + nt * 1024 + lane * 16);
#pragma unroll
            for (int mt = 0; mt < 4; ++mt) {
                acc[mt][nt] = __builtin_amdgcn_mfma_f32_16x16x32_bf16(ahi[mt], bh, acc[mt][nt], 0, 0, 0);
                acc[mt][nt] = __builtin_amdgcn_mfma_f32_16x16x32_bf16(ahi[mt], bl, acc[mt][nt], 0, 0, 0);
                acc[mt][nt] = __builtin_amdgcn_mfma_f32_16x16x32_bf16(alo[mt], bh, acc[mt][nt], 0, 0, 0);
            }
        }
    }
    __syncthreads();

    // ---- per-wave top-2 over its 64 t, per filter; tuples to LDS (overlay)
    float4* Tup = (float4*)smem;                          // [8 waves][64 f] = 8KB
#pragma unroll
    for (int nt = 0; nt < 4; ++nt) {
        float v1 = -INFINITY, v2 = -INFINITY;
        int   i1 = 0, i2 = 0;
#pragma unroll
        for (int mt = 0; mt < 4; ++mt)
#pragma unroll
            for (int r = 0; r < 4; ++r) {                 // ascending t within lane
                const int   t = w * 64 + mt * 16 + h * 4 + r;
                const float v = acc[mt][nt][r];
                if (v > v1)      { v2 = v1; i2 = i1; v1 = v; i1 = t; }
                else if (v > v2) { v2 = v;  i2 = t; }
            }
        // butterfly over the 4 lane-groups sharing f (xor 16, 32)
#pragma unroll
        for (int off = 16; off <= 32; off <<= 1) {
            const float bv1 = __shfl_xor(v1, off);
            const int   bi1 = __shfl_xor(i1, off);
            const float bv2 = __shfl_xor(v2, off);
            const int   bi2 = __shfl_xor(i2, off);
            const bool aTop = (v1 > bv1) || (v1 == bv1 && i1 < bi1);
            float nv1, nv2; int ni1, ni2;
            if (aTop) {
                nv1 = v1; ni1 = i1;
                const bool s = (v2 > bv1) || (v2 == bv1 && i2 < bi1);
                nv2 = s ? v2 : bv1; ni2 = s ? i2 : bi1;
            } else {
                nv1 = bv1; ni1 = bi1;
                const bool s = (bv2 > v1) || (bv2 == v1 && bi2 < i1);
                nv2 = s ? bv2 : v1; ni2 = s ? bi2 : i1;
            }
            v1 = nv1; i1 = ni1; v2 = nv2; i2 = ni2;
        }
        if (lane < 16)
            Tup[w * 64 + nt * 16 + lane] =
                make_float4(v1, __int_as_float(i1), v2, __int_as_float(i2));
    }
    __syncthreads();

    // ---- merge 8 wave-tuples per f; f64 refine only on near-ties; scatter
#pragma unroll 1
    for (int jj = 0; jj < 8; ++jj) {
        const int fr = w * 8 + jj;
        const int gf = fBase + fr;
        if (gf >= F_) continue;                           // wave-uniform
        float v1 = -INFINITY, v2 = -INFINITY;
        int   i1 = 0, i2 = 0;
#pragma unroll 1
        for (int ww = 0; ww < 8; ++ww) {                  // ascending t-ranges
            const float4 tp = Tup[ww * 64 + fr];          // broadcast read
            const float u1 = tp.x, u2 = tp.z;
            const int   j1 = __float_as_int(tp.y), j2 = __float_as_int(tp.w);
            if (u1 > v1) {
                const bool s = (v1 >= u2);                // tie -> earlier index (v-side)
                v2 = s ? v1 : u2; i2 = s ? i1 : j2;
                v1 = u1; i1 = j1;
            } else if (u1 > v2) { v2 = u1; i2 = j1; }
        }
        const float cb = conv_b[gf];
        const float dw = fc_w[F_ + gf] - fc_w[gf];
        double mv = 0.0; int idx = 0;
        if (v1 - v2 > 4e-4f) {                            // gap >> bf16x3 error
            mv = (double)v1 + (double)cb; idx = i1;
        } else {                                          // rare: exact f64 tiebreak
            const float* e1 = emb + (size_t)inp[b * L_ + i1] * D_;
            const float* e2 = emb + (size_t)inp[b * L_ + i2] * D_;
            const float* wf = conv_w + (size_t)gf * D_;
            double p1 = 0.0, p2 = 0.0;
            for (int d = lane; d < D_; d += 64) {
                const double wd = (double)wf[d];
                p1 = fma((double)e1[d], wd, p1);
                p2 = fma((double)e2[d], wd, p2);
            }
            for (int off = 32; off; off >>= 1) {
                p1 += __shfl_down(p1, off);
                p2 += __shfl_down(p2, off);
            }
            const double d1 = p1 + (double)cb, d2 = p2 + (double)cb;  // lane0 valid
            if (d2 > d1) { mv = d2; idx = i2; }
            else         { mv = d1; idx = i1; }
        }
        if (lane == 0 && mv > 0.0)
            atomicAdd(out + b * L_ + idx, (float)(mv * (double)dw));
    }
}

// ================= fallback (Round-0 kernel, PASSED) if ws too small =========
#define TFo 32
#define DKo 16
#define NCHo 19
__global__ __launch_bounds__(256, 2)
void conv_max_scatter(const int* __restrict__ inp,
                      const float* __restrict__ emb,
                      const float* __restrict__ conv_w,
                      const float* __restrict__ conv_b,
                      const float* __restrict__ fc_w,
                      float* __restrict__ out) {
    __shared__ float E_s[DKo][L_];
    __shared__ float W_s[DKo][TFo + 1];
    __shared__ int   inp_s[L_];
    const int tid = threadIdx.x, b = blockIdx.y, fBase = blockIdx.x * TFo;
    const int lane = tid & 63, wave = tid >> 6, f0 = wave * 8;
    inp_s[tid] = inp[b * L_ + tid];
    inp_s[tid + 256] = inp[b * L_ + tid + 256];
    __syncthreads();
    float acc[8][8];
#pragma unroll
    for (int k = 0; k < 8; ++k)
#pragma unroll
        for (int j = 0; j < 8; ++j) acc[k][j] = 0.f;
    for (int c = 0; c < NCHo; ++c) {
        const int d0 = c * DKo;
#pragma unroll
        for (int e = 0; e < 2; ++e) {
            const int t = tid * 2 + e;
            const float* rowp = emb + (size_t)inp_s[t] * D_ + d0;
#pragma unroll
            for (int s = 0; s < 4; ++s) {
                float4 v;
                if (d0 + s * 4 < D_) v = *(const float4*)(rowp + s * 4);
                else                 v = make_float4(0.f, 0.f, 0.f, 0.f);
                E_s[s * 4 + 0][t] = v.x; E_s[s * 4 + 1][t] = v.y;
                E_s[s * 4 + 2][t] = v.z; E_s[s * 4 + 3][t] = v.w;
            }
        }
#pragma unroll
        for (int e = 0; e < 2; ++e) {
            const int d = tid & 15, f = (tid >> 4) + e * 16, gf = fBase + f;
            float v = 0.f;
            if (gf < F_ && d0 + d < D_) v = conv_w[(size_t)gf * D_ + d0 + d];
            W_s[d][f] = v;
        }
        __syncthreads();
#pragma unroll
        for (int d = 0; d < DKo; ++d) {
            float wv[8], ev[8];
#pragma unroll
            for (int j = 0; j < 8; ++j) wv[j] = W_s[d][f0 + j];
#pragma unroll
            for (int k = 0; k < 8; ++k) ev[k] = E_s[d][lane + 64 * k];
#pragma unroll
            for (int k = 0; k < 8; ++k)
#pragma unroll
                for (int j = 0; j < 8; ++j) acc[k][j] = fmaf(ev[k], wv[j], acc[k][j]);
        }
        __syncthreads();
    }
    float v1a[8], v2a[8]; int i1a[8], i2a[8];
#pragma unroll
    for (int j = 0; j < 8; ++j) {
        float v1 = -INFINITY, v2 = -INFINITY; int i1 = 0, i2 = 0;
#pragma unroll
        for (int k = 0; k < 8; ++k) {
            const int t = lane + 64 * k; const float v = acc[k][j];
            if (v > v1) { v2 = v1; i2 = i1; v1 = v; i1 = t; }
            else if (v > v2) { v2 = v; i2 = t; }
        }
        for (int off = 1; off < 64; off <<= 1) {
            const float bv1 = __shfl_xor(v1, off); const int bi1 = __shfl_xor(i1, off);
            const float bv2 = __shfl_xor(v2, off); const int bi2 = __shfl_xor(i2, off);
            const bool aTop = (v1 > bv1) || (v1 == bv1 && i1 < bi1);
            float nv1, nv2; int ni1, ni2;
            if (aTop) {
                nv1 = v1; ni1 = i1;
                const bool s = (v2 > bv1) || (v2 == bv1 && i2 < bi1);
                nv2 = s ? v2 : bv1; ni2 = s ? i2 : bi1;
            } else {
                nv1 = bv1; ni1 = bi1;
                const bool s = (bv2 > v1) || (bv2 == v1 && bi2 < i1);
                nv2 = s ? bv2 : v1; ni2 = s ? bi2 : i1;
            }
            v1 = nv1; i1 = ni1; v2 = nv2; i2 = ni2;
        }
        v1a[j] = v1; i1a[j] = i1; v2a[j] = v2; i2a[j] = i2;
    }
#pragma unroll 1
    for (int j = 0; j < 8; ++j) {
        const int gf = fBase + f0 + j;
        if (gf >= F_) continue;
        const int i1 = i1a[j], i2 = i2a[j];
        const float* e1 = emb + (size_t)inp_s[i1] * D_;
        const float* e2 = emb + (size_t)inp_s[i2] * D_;
        const float* wf = conv_w + (size_t)gf * D_;
        double p1 = 0.0, p2 = 0.0;
        for (int d = lane; d < D_; d += 64) {
            const double wd = (double)wf[d];
            p1 = fma((double)e1[d], wd, p1);
            p2 = fma((double)e2[d], wd, p2);
        }
        for (int off = 32; off; off >>= 1) { p1 += __shfl_down(p1, off); p2 += __shfl_down(p2, off); }
        if (lane == 0) {
            const double cb = (double)conv_b[gf];
            const double d1 = p1 + cb, d2 = p2 + cb;
            int idx; double mv;
            if (d2 > d1) { idx = i2; mv = d2; } else { idx = i1; mv = d1; }
            if (mv > 0.0)
                atomicAdd(&out[b * L_ + idx], (float)(mv * (double)(fc_w[F_ + gf] - fc_w[gf])));
        }
    }
}

// ============================================================================
extern "C" void kernel_launch(void* const* d_in, const int* in_sizes, int n_in,
                              void* d_out, int out_size, void* d_ws, size_t ws_size,
                              hipStream_t stream) {
    const int*   inp    = (const int*)d_in[0];
    const float* emb    = (const float*)d_in[1];
    const float* conv_w = (const float*)d_in[2];
    const float* conv_b = (const float*)d_in[3];
    const float* fc_w   = (const float*)d_in[4];
    const float* fc_b   = (const float*)d_in[5];
    float* out = (float*)d_out;

    init_token_kernel<<<dim3((B_ * L_ + 255) / 256), dim3(256), 0, stream>>>(out, fc_b);

    if (ws_size >= WS_NEED) {
        char* ws = (char*)d_ws;
        unsigned int* ehi = (unsigned int*)(ws + EHI_OFF);
        unsigned int* elo = (unsigned int*)(ws + ELO_OFF);
        unsigned int* whi = (unsigned int*)(ws + WHI_OFF);
        unsigned int* wlo = (unsigned int*)(ws + WLO_OFF);
        convert_E<<<dim3(40960), dim3(256), 0, stream>>>(inp, emb, ehi, elo);
        convert_W<<<dim3(640),   dim3(256), 0, stream>>>(conv_w, whi, wlo);
        gemm_max_scatter<<<dim3(2048), dim3(512), 0, stream>>>(
            inp, emb, conv_w, conv_b, fc_w,
            (const char*)ehi, (const char*)elo, (const char*)whi, (const char*)wlo, out);
    } else {
        conv_max_scatter<<<dim3(32, 128), dim3(256), 0, stream>>>(
            inp, emb, conv_w, conv_b, fc_w, out);
    }
}